// Round 5
// baseline (409.095 us; speedup 1.0000x reference)
//
#include <hip/hip_runtime.h>
#include <stdint.h>
#include <math.h>

#define B_ 16
#define C_ 256
#define O_ 256
#define L_ 8192
#define NBL (B_*L_)
#define EPS_ 1e-5

typedef unsigned short ushort_t;
typedef _Float16 f16x8 __attribute__((ext_vector_type(8)));
typedef float f32x4 __attribute__((ext_vector_type(4)));

__device__ inline float wred_f(float v) {
#pragma unroll
    for (int o = 32; o > 0; o >>= 1) v += __shfl_down(v, o, 64);
    return v;
}
__device__ inline int wred_i(int v) {
#pragma unroll
    for (int o = 32; o > 0; o >>= 1) v += __shfl_down(v, o, 64);
    return v;
}
__device__ inline double wred_d(double v) {
#pragma unroll
    for (int o = 32; o > 0; o >>= 1) v += __shfl_down(v, o, 64);
    return v;
}

__device__ inline ushort_t f16bits(float x) {
    union { _Float16 h; ushort_t u; } c; c.h = (_Float16)x; return c.u;
}

// ---- kernel 1: per-(channel, batch-quarter) partial sums for BN stats ----
__global__ __launch_bounds__(256) void k_bnpart(const float* __restrict__ x,
                                                double* __restrict__ pS,
                                                double* __restrict__ pS2) {
    const int bid = blockIdx.x;
    const int c = bid >> 2;
    const int part = bid & 3;
    const int tid = threadIdx.x;
    const int lane = tid & 63, w = tid >> 6;
    double s = 0.0, s2 = 0.0;
#pragma unroll
    for (int b = 0; b < 4; ++b) {
        const float4* p = (const float4*)(x + ((size_t)(part * 4 + b) * C_ + c) * L_);
#pragma unroll
        for (int j = 0; j < 8; ++j) {
            float4 q = p[j * 256 + tid];
            s  += (double)q.x + (double)q.y + (double)q.z + (double)q.w;
            s2 += (double)q.x * q.x + (double)q.y * q.y + (double)q.z * q.z + (double)q.w * q.w;
        }
    }
    s = wred_d(s); s2 = wred_d(s2);
    __shared__ double sv[4], sv2[4];
    if (lane == 0) { sv[w] = s; sv2[w] = s2; }
    __syncthreads();
    if (tid == 0) {
        pS[bid]  = sv[0] + sv[1] + sv[2] + sv[3];
        pS2[bid] = sv2[0] + sv2[1] + sv2[2] + sv2[3];
    }
}

// ---- kernel 2: weight-norm partial sumsq ----
__global__ __launch_bounds__(256) void k_vpart(const float* __restrict__ v,
                                               double* __restrict__ pv) {
    const int tid = threadIdx.x;
    const float4 q = ((const float4*)v)[(size_t)blockIdx.x * 256 + tid];
    double s2 = (double)q.x * q.x + (double)q.y * q.y + (double)q.z * q.z + (double)q.w * q.w;
    s2 = wred_d(s2);
    __shared__ double sv[4];
    const int lane = tid & 63, w = tid >> 6;
    if (lane == 0) sv[w] = s2;
    __syncthreads();
    if (tid == 0) pv[blockIdx.x] = sv[0] + sv[1] + sv[2] + sv[3];
}

// ---- kernel 3: finalize stats ----
__global__ __launch_bounds__(256) void k_finalize(const float* __restrict__ gamma,
                                                  const float* __restrict__ beta,
                                                  const float* __restrict__ g,
                                                  const double* __restrict__ pS,
                                                  const double* __restrict__ pS2,
                                                  const double* __restrict__ pv,
                                                  float* __restrict__ ab,
                                                  float* __restrict__ invn) {
    const int tid = threadIdx.x;
    const int lane = tid & 63, w = tid >> 6;
    double s2 = (tid < 192) ? pv[tid] : 0.0;
    s2 = wred_d(s2);
    __shared__ double sv[4];
    if (lane == 0) sv[w] = s2;
    __syncthreads();
    if (tid == 0) invn[0] = (float)((double)g[0] / sqrt(sv[0] + sv[1] + sv[2] + sv[3]));

    const int c = tid;
    double s  = pS[c * 4] + pS[c * 4 + 1] + pS[c * 4 + 2] + pS[c * 4 + 3];
    double ss = pS2[c * 4] + pS2[c * 4 + 1] + pS2[c * 4 + 2] + pS2[c * 4 + 3];
    const double N = (double)NBL;
    double mean = s / N;
    double var = ss / N - mean * mean;
    double rstd = 1.0 / sqrt(var + EPS_);
    double a = (double)gamma[c] * rstd;
    ab[c] = (float)a;
    ab[C_ + c] = (float)((double)beta[c] - mean * a);
}

// ---- kernel 3b: weight prep, f16 single, fragment-major [tap][o16][c8chunk][o&15][c&7];
//      block 0 also zeros the 9 KB halo zero-page ----
__global__ __launch_bounds__(256) void k_wprep(const float* __restrict__ v,
                                               const float* __restrict__ invn,
                                               ushort_t* __restrict__ W,
                                               ushort_t* __restrict__ zp8) {
    const int o = blockIdx.x;
    const int c = threadIdx.x;
    const float sc = invn[0];
    if (blockIdx.x == 0) {
        for (int i = threadIdx.x; i < 4608; i += 256) zp8[i] = 0;
    }
#pragma unroll
    for (int tap = 0; tap < 3; ++tap) {
        float w = v[((size_t)o * C_ + c) * 3 + tap] * sc;
        int idx = ((tap * 16 + (o >> 4)) * 32 + (c >> 3)) * 128 + (o & 15) * 8 + (c & 7);
        W[idx] = f16bits(w);
    }
}

// ---- kernel 4a: tau per row (Michelot projection), no s write ----
// One barrier per iteration: parity-double-buffered partials; every thread
// redundantly computes tau from the 4 per-wave partials (no tid0 broadcast).
// Counts reduced as float (exact: counts <= 8192 < 2^24).
__global__ __launch_bounds__(256) void k_tau(const float* __restrict__ x,
                                             const float* __restrict__ ab,
                                             float* __restrict__ tauv) {
    const int row = blockIdx.x;          // b*C + c
    const int c = row & (C_ - 1);
    const int tid = threadIdx.x;
    const int lane = tid & 63, w = tid >> 6;
    __shared__ float svf[2][4];
    __shared__ float svc[2][4];

    const float a = ab[c];
    const float bb = ab[C_ + c];
    const float4* px = (const float4*)(x + (size_t)row * L_);

    float z[32];
    float sm = 0.f;
#pragma unroll
    for (int j = 0; j < 8; ++j) {
        float4 q = px[j * 256 + tid];
        float z0 = fmaf(a, q.x, bb), z1 = fmaf(a, q.y, bb);
        float z2 = fmaf(a, q.z, bb), z3 = fmaf(a, q.w, bb);
        z[4 * j] = z0; z[4 * j + 1] = z1; z[4 * j + 2] = z2; z[4 * j + 3] = z3;
        sm += z0 + z1 + z2 + z3;
    }
    sm = wred_f(sm);
    if (lane == 0) svf[0][w] = sm;
    __syncthreads();
    float tau = (svf[0][0] + svf[0][1] + svf[0][2] + svf[0][3] - 1.f) * (1.f / (float)L_);
    int prev = L_;
#pragma unroll 1
    for (int it = 0; it < 100; ++it) {
        float ls = 0.f, lc = 0.f;
#pragma unroll
        for (int j = 0; j < 32; ++j) {
            if (z[j] > tau) { ls += z[j]; lc += 1.f; }
        }
        ls = wred_f(ls); lc = wred_f(lc);
        const int pb = (it & 1) ^ 1;     // it0 writes buf1 (init used buf0)
        if (lane == 0) { svf[pb][w] = ls; svc[pb][w] = lc; }
        __syncthreads();
        float gs = svf[pb][0] + svf[pb][1] + svf[pb][2] + svf[pb][3];
        float gc = svc[pb][0] + svc[pb][1] + svc[pb][2] + svc[pb][3];
        tau = (gs - 1.f) / gc;
        int gci = (int)gc;
        if (gci == prev) break;
        prev = gci;
    }
    if (tid == 0) tauv[row] = tau;
}

// ---- kernel 4b (fast): fused normalize + sparsemax-apply + f16 + transpose ----
// x[b][c][l] -> Sh[b][l>>4][c>>3][l&15][c&7] f16, grid (L/32, B), 256 thr
__global__ __launch_bounds__(256) void k_applyT(const float* __restrict__ x,
                                                const float* __restrict__ ab,
                                                const float* __restrict__ tauv,
                                                ushort_t* __restrict__ Sh) {
    __shared__ float sT[32 * 256];
    const int lt = blockIdx.x * 32;
    const int b = blockIdx.y;
    const int tid = threadIdx.x;
    {
        const int c = tid;
        const float a = ab[c];
        const float bb = ab[C_ + c];
        const float tv = tauv[b * C_ + c];
        const float* src = x + ((size_t)b * C_ + c) * L_ + lt;
        const int qg = c >> 2, cr = c & 3;
#pragma unroll
        for (int j = 0; j < 8; ++j) {
            float4 v4 = ((const float4*)src)[j];
            int l0 = j * 4;
            float s0 = fmaxf(fmaf(a, v4.x, bb) - tv, 0.f);
            float s1 = fmaxf(fmaf(a, v4.y, bb) - tv, 0.f);
            float s2 = fmaxf(fmaf(a, v4.z, bb) - tv, 0.f);
            float s3 = fmaxf(fmaf(a, v4.w, bb) - tv, 0.f);
            sT[(l0 + 0) * 256 + (((qg ^ ((l0 + 0) & 7)) << 2) | cr)] = s0;
            sT[(l0 + 1) * 256 + (((qg ^ ((l0 + 1) & 7)) << 2) | cr)] = s1;
            sT[(l0 + 2) * 256 + (((qg ^ ((l0 + 2) & 7)) << 2) | cr)] = s2;
            sT[(l0 + 3) * 256 + (((qg ^ ((l0 + 3) & 7)) << 2) | cr)] = s3;
        }
    }
    __syncthreads();
    const int l = tid & 31, c8 = tid >> 5;
    ushort_t hb[32];
#pragma unroll
    for (int i = 0; i < 8; ++i) {
        int qq = c8 * 8 + i;
        const float4 v4 = *(const float4*)&sT[l * 256 + ((qq ^ (l & 7)) << 2)];
        hb[i * 4 + 0] = f16bits(v4.x);
        hb[i * 4 + 1] = f16bits(v4.y);
        hb[i * 4 + 2] = f16bits(v4.z);
        hb[i * 4 + 3] = f16bits(v4.w);
    }
    const size_t tbase = (((size_t)b * 512 + ((lt + l) >> 4)) * 32) * 128 + (l & 15) * 8;
#pragma unroll
    for (int i = 0; i < 4; ++i) {
        size_t idx = tbase + (size_t)(c8 * 4 + i) * 128;
        *(uint4*)(Sh + idx) = ((const uint4*)hb)[i];
    }
}

// ---- legacy fallback: sparsemax writing s fp32 (to d_out) ----
__global__ __launch_bounds__(256) void k_sparsemax(const float* __restrict__ x,
                                                   const float* __restrict__ ab,
                                                   float* __restrict__ sout) {
    const int row = blockIdx.x;
    const int c = row & (C_ - 1);
    const int tid = threadIdx.x;
    const int lane = tid & 63, w = tid >> 6;
    __shared__ float svf[4];
    __shared__ int svi[4];
    __shared__ float s_tau;
    __shared__ int s_cnt;

    const float a = ab[c];
    const float bb = ab[C_ + c];
    const float4* px = (const float4*)(x + (size_t)row * L_);
    float4* ps = (float4*)(sout + (size_t)row * L_);

    float z[32];
    float sm = 0.f;
#pragma unroll
    for (int j = 0; j < 8; ++j) {
        float4 q = px[j * 256 + tid];
        float z0 = fmaf(a, q.x, bb), z1 = fmaf(a, q.y, bb);
        float z2 = fmaf(a, q.z, bb), z3 = fmaf(a, q.w, bb);
        z[4 * j] = z0; z[4 * j + 1] = z1; z[4 * j + 2] = z2; z[4 * j + 3] = z3;
        sm += z0 + z1 + z2 + z3;
    }
    sm = wred_f(sm);
    if (lane == 0) svf[w] = sm;
    __syncthreads();
    if (tid == 0) s_tau = (svf[0] + svf[1] + svf[2] + svf[3] - 1.f) * (1.f / (float)L_);
    __syncthreads();
    float tau = s_tau;
    int prev = L_;
    for (int it = 0; it < 100; ++it) {
        float ls = 0.f; int lc = 0;
#pragma unroll
        for (int j = 0; j < 32; ++j) {
            if (z[j] > tau) { ls += z[j]; ++lc; }
        }
        ls = wred_f(ls); lc = wred_i(lc);
        if (lane == 0) { svf[w] = ls; svi[w] = lc; }
        __syncthreads();
        if (tid == 0) {
            int gc = svi[0] + svi[1] + svi[2] + svi[3];
            float gs = svf[0] + svf[1] + svf[2] + svf[3];
            s_cnt = gc;
            s_tau = (gs - 1.f) / (float)gc;
        }
        __syncthreads();
        int gc = s_cnt;
        if (gc == prev) break;
        prev = gc;
        tau = s_tau;
    }
#pragma unroll
    for (int j = 0; j < 8; ++j) {
        float4 o;
        o.x = fmaxf(z[4 * j]     - tau, 0.f);
        o.y = fmaxf(z[4 * j + 1] - tau, 0.f);
        o.z = fmaxf(z[4 * j + 2] - tau, 0.f);
        o.w = fmaxf(z[4 * j + 3] - tau, 0.f);
        ps[j * 256 + tid] = o;
    }
}

// ---- legacy fallback: transpose fp32 s -> fragment-major f16 ----
__global__ __launch_bounds__(256) void k_transF16(const float* __restrict__ s,
                                                  ushort_t* __restrict__ Sh) {
    __shared__ float sT[32 * 256];
    const int lt = blockIdx.x * 32;
    const int b = blockIdx.y;
    const int tid = threadIdx.x;
    {
        const int c = tid;
        const float* src = s + ((size_t)b * C_ + c) * L_ + lt;
        const int qg = c >> 2, cr = c & 3;
#pragma unroll
        for (int j = 0; j < 8; ++j) {
            float4 v4 = ((const float4*)src)[j];
            int l0 = j * 4;
            sT[(l0 + 0) * 256 + (((qg ^ ((l0 + 0) & 7)) << 2) | cr)] = v4.x;
            sT[(l0 + 1) * 256 + (((qg ^ ((l0 + 1) & 7)) << 2) | cr)] = v4.y;
            sT[(l0 + 2) * 256 + (((qg ^ ((l0 + 2) & 7)) << 2) | cr)] = v4.z;
            sT[(l0 + 3) * 256 + (((qg ^ ((l0 + 3) & 7)) << 2) | cr)] = v4.w;
        }
    }
    __syncthreads();
    const int l = tid & 31, c8 = tid >> 5;
    ushort_t hb[32];
#pragma unroll
    for (int i = 0; i < 8; ++i) {
        int qq = c8 * 8 + i;
        const float4 v4 = *(const float4*)&sT[l * 256 + ((qq ^ (l & 7)) << 2)];
        hb[i * 4 + 0] = f16bits(v4.x);
        hb[i * 4 + 1] = f16bits(v4.y);
        hb[i * 4 + 2] = f16bits(v4.z);
        hb[i * 4 + 3] = f16bits(v4.w);
    }
    const size_t tbase = (((size_t)b * 512 + ((lt + l) >> 4)) * 32) * 128 + (l & 15) * 8;
#pragma unroll
    for (int i = 0; i < 4; ++i) {
        size_t idx = tbase + (size_t)(c8 * 4 + i) * 128;
        *(uint4*)(Sh + idx) = ((const uint4*)hb)[i];
    }
}

// ---- kernel 5: conv, f16 MFMA, LDS-staged B (one barrier), A from global ----
// 64 O x 64 L per wave (acc[4][4] = 64 regs); block 256 thr = 4 waves;
// block tile = 256 O x 64 L; grid (L/64 = 128, B = 16).
// unroll 2 on ck-loop: allow compiler to prefetch iteration k+1's A/B loads
// under iteration k's MFMAs (unroll 1 forbade cross-iteration scheduling).
// launch_bounds(256,3): keep VGPR <= ~170 so >=3 blocks/CU stay resident
// (LDS at 32 KB allows 5 blocks/CU).
template<bool EDGE>
__device__ __forceinline__ void conv_core(const ushort_t* __restrict__ Sg,
                                          const ushort_t* __restrict__ W,
                                          const ushort_t* __restrict__ zp8,
                                          float* __restrict__ y,
                                          ushort_t* sB) {
    const int lt = blockIdx.x * 64;
    const int b = blockIdx.y;
    const int tid = threadIdx.x;
    const int wv = tid >> 6, lane = tid & 63;
    const int ml = lane & 15, qd = lane >> 4;

    const ushort_t* SgB = Sg + (size_t)b * 512 * 4096;   // 512 tiles/batch, 4096 elem/tile

    // ---- stage: one contiguous 32 KB global->LDS memcpy ----
    {
        const ushort_t* gsrc = SgB + (size_t)(lt >> 4) * 4096;
        char* lb = (char*)sB;
#pragma unroll
        for (int it = 0; it < 8; ++it) {
            int u = it * 256 + tid;
            __builtin_amdgcn_global_load_lds(
                (const __attribute__((address_space(1))) uint32_t*)(gsrc + u * 8),
                (__attribute__((address_space(3))) uint32_t*)(lb + u * 16),
                16, 0, 0);
        }
    }

    // A-fragment global pointers (per-lane), ck=0 base
    const ushort_t* pA[3][4];
#pragma unroll
    for (int tap = 0; tap < 3; ++tap)
#pragma unroll
        for (int mi = 0; mi < 4; ++mi)
            pA[tap][mi] = W + ((tap * 16 + wv * 4 + mi) * 32 + qd) * 128 + ml * 8;

    // B-fragment LDS byte offsets (ck=0); [0][0] and [2][3] replaced by global
    int bOff[3][4];
#pragma unroll
    for (int tap = 0; tap < 3; ++tap)
#pragma unroll
        for (int ni = 0; ni < 4; ++ni) {
            int rc = ni * 16 + ml + tap - 1;
            int rcc = rc & 63;               // avoid negative shifts; boundary frags unused
            bOff[tap][ni] = ((rcc >> 4) << 13) + (qd << 8) + ((rcc & 15) << 4);
        }

    // boundary fragments via global (per-lane pointers)
    const int ccgL = lt + ml - 1;        // tap0 ni0
    const int ccgR = lt + 49 + ml;       // tap2 ni3
    const ushort_t* gpL;
    const ushort_t* gpR;
    {
        int cl = ccgL & (L_ - 1);
        int cr2 = ccgR & (L_ - 1);
        const ushort_t* pl = SgB + (((size_t)(cl >> 4) * 32 + qd) * 128 + (cl & 15) * 8);
        const ushort_t* pr = SgB + (((size_t)(cr2 >> 4) * 32 + qd) * 128 + (cr2 & 15) * 8);
        if (EDGE) {
            if (ccgL < 0)   pl = zp8;
            if (ccgR >= L_) pr = zp8;
        }
        gpL = pl; gpR = pr;
    }

    f32x4 acc[4][4];
#pragma unroll
    for (int mi = 0; mi < 4; ++mi)
#pragma unroll
        for (int ni = 0; ni < 4; ++ni) acc[mi][ni] = (f32x4)0.f;

    __syncthreads();

    const char* sBc = (const char*)sB;
#pragma unroll 2
    for (int ck = 0; ck < 8; ++ck) {
        const int lofs = ck * 1024;        // bytes: 4 chunks * 256 B
        const int gofs = ck * 512;         // elements
#pragma unroll
        for (int tap = 0; tap < 3; ++tap) {
            f16x8 Bf[4];
#pragma unroll
            for (int ni = 0; ni < 4; ++ni) {
                if (tap == 0 && ni == 0)
                    Bf[ni] = *(const f16x8*)(gpL + gofs);
                else if (tap == 2 && ni == 3)
                    Bf[ni] = *(const f16x8*)(gpR + gofs);
                else
                    Bf[ni] = *(const f16x8*)(sBc + bOff[tap][ni] + lofs);
            }
#pragma unroll
            for (int mi = 0; mi < 4; ++mi) {
                f16x8 Af = *(const f16x8*)(pA[tap][mi] + gofs);
#pragma unroll
                for (int ni = 0; ni < 4; ++ni)
                    acc[mi][ni] = __builtin_amdgcn_mfma_f32_16x16x32_f16(Af, Bf[ni], acc[mi][ni], 0, 0, 0);
            }
        }
    }

    // epilogue: ReLU + store. C/D: col = lane&15 (l), row = qd*4+r (o)
#pragma unroll
    for (int mi = 0; mi < 4; ++mi) {
#pragma unroll
        for (int ni = 0; ni < 4; ++ni) {
            int lg = lt + ni * 16 + ml;
#pragma unroll
            for (int r = 0; r < 4; ++r) {
                int og = wv * 64 + mi * 16 + qd * 4 + r;
                y[((size_t)b * O_ + og) * L_ + lg] = fmaxf(acc[mi][ni][r], 0.f);
            }
        }
    }
}

__global__ __launch_bounds__(256, 3) void k_conv_f16(const ushort_t* __restrict__ Sg,
                                                     const ushort_t* __restrict__ W,
                                                     const ushort_t* __restrict__ zp8,
                                                     float* __restrict__ y) {
    __shared__ ushort_t sB[16384];   // single 32 KB allocation shared by both paths
    if (blockIdx.x == 0 || blockIdx.x == (L_ / 64) - 1)
        conv_core<true>(Sg, W, zp8, y, sB);
    else
        conv_core<false>(Sg, W, zp8, y, sB);
}

extern "C" void kernel_launch(void* const* d_in, const int* in_sizes, int n_in,
                              void* d_out, int out_size, void* d_ws, size_t ws_size,
                              hipStream_t stream) {
    const float* x     = (const float*)d_in[0];
    const float* gamma = (const float*)d_in[1];
    const float* beta  = (const float*)d_in[2];
    const float* v     = (const float*)d_in[3];
    const float* g     = (const float*)d_in[4];
    float* y = (float*)d_out;

    char* ws = (char*)d_ws;
    float*  ab   = (float*)ws;                    // 512 floats
    float*  invn = (float*)(ws + 2048);           // 1 float
    double* pv   = (double*)(ws + 4096);          // 192 doubles
    double* pS   = (double*)(ws + 8192);          // 1024 doubles
    double* pS2  = (double*)(ws + 16384);         // 1024 doubles
    float*  tauv = (float*)(ws + 24576);          // 4096 floats (16 KB)
    ushort_t* W  = (ushort_t*)(ws + 49152);       // 196608 ushorts = 384 KB
    ushort_t* zp8 = (ushort_t*)(ws + 49152 + 393216);  // 4608 ushorts (9 KB zeros)

    const size_t shOff = 1 << 20;                 // Sh at ws + 1 MB
    const size_t need = shOff + (size_t)B_ * L_ * C_ * sizeof(ushort_t);  // 1 MB + 64 MB
    const bool fast = (ws_size >= need);

    k_bnpart<<<1024, 256, 0, stream>>>(x, pS, pS2);
    k_vpart<<<192, 256, 0, stream>>>(v, pv);
    k_finalize<<<1, 256, 0, stream>>>(gamma, beta, g, pS, pS2, pv, ab, invn);
    k_wprep<<<256, 256, 0, stream>>>(v, invn, W, zp8);

    const ushort_t* Sg;
    if (fast) {
        ushort_t* Sh = (ushort_t*)(ws + shOff);
        k_tau<<<4096, 256, 0, stream>>>(x, ab, tauv);
        dim3 tg(L_ / 32, B_);
        k_applyT<<<tg, 256, 0, stream>>>(x, ab, tauv, Sh);
        Sg = Sh;
    } else {
        // legacy: s fp32 round-trips through d_out; Sh f16 lives in x's buffer
        float* sbuf = (float*)d_out;
        ushort_t* Sh = (ushort_t*)d_in[0];
        k_sparsemax<<<4096, 256, 0, stream>>>(x, ab, sbuf);
        dim3 tg(L_ / 32, B_);
        k_transF16<<<tg, 256, 0, stream>>>(sbuf, Sh);
        Sg = Sh;
    }

    dim3 cgrid(L_ / 64, B_);
    k_conv_f16<<<cgrid, 256, 0, stream>>>(Sg, W, zp8, y);
}

// Round 6
// 370.081 us; speedup vs baseline: 1.1054x; 1.1054x over previous
//
#include <hip/hip_runtime.h>
#include <stdint.h>
#include <math.h>

#define B_ 16
#define C_ 256
#define O_ 256
#define L_ 8192
#define NBL (B_*L_)
#define EPS_ 1e-5

typedef unsigned short ushort_t;
typedef _Float16 f16x8 __attribute__((ext_vector_type(8)));
typedef float f32x4 __attribute__((ext_vector_type(4)));

__device__ inline float wred_f(float v) {
#pragma unroll
    for (int o = 32; o > 0; o >>= 1) v += __shfl_down(v, o, 64);
    return v;
}
__device__ inline int wred_i(int v) {
#pragma unroll
    for (int o = 32; o > 0; o >>= 1) v += __shfl_down(v, o, 64);
    return v;
}
__device__ inline double wred_d(double v) {
#pragma unroll
    for (int o = 32; o > 0; o >>= 1) v += __shfl_down(v, o, 64);
    return v;
}

__device__ inline ushort_t f16bits(float x) {
    union { _Float16 h; ushort_t u; } c; c.h = (_Float16)x; return c.u;
}

// ---- kernel 1 (merged): BN partial sums (blocks 0..1023) + weight-norm
//      partial sumsq (blocks 1024..1215). Bodies identical to the verified
//      k_bnpart / k_vpart; merged to save one launch. ----
__global__ __launch_bounds__(256) void k_stats(const float* __restrict__ x,
                                               const float* __restrict__ v,
                                               double* __restrict__ pS,
                                               double* __restrict__ pS2,
                                               double* __restrict__ pv) {
    const int tid = threadIdx.x;
    const int lane = tid & 63, w = tid >> 6;
    __shared__ double sv[4], sv2[4];
    if (blockIdx.x < 1024) {
        const int bid = blockIdx.x;
        const int c = bid >> 2;
        const int part = bid & 3;
        double s = 0.0, s2 = 0.0;
#pragma unroll
        for (int b = 0; b < 4; ++b) {
            const float4* p = (const float4*)(x + ((size_t)(part * 4 + b) * C_ + c) * L_);
#pragma unroll
            for (int j = 0; j < 8; ++j) {
                float4 q = p[j * 256 + tid];
                s  += (double)q.x + (double)q.y + (double)q.z + (double)q.w;
                s2 += (double)q.x * q.x + (double)q.y * q.y + (double)q.z * q.z + (double)q.w * q.w;
            }
        }
        s = wred_d(s); s2 = wred_d(s2);
        if (lane == 0) { sv[w] = s; sv2[w] = s2; }
        __syncthreads();
        if (tid == 0) {
            pS[bid]  = sv[0] + sv[1] + sv[2] + sv[3];
            pS2[bid] = sv2[0] + sv2[1] + sv2[2] + sv2[3];
        }
    } else {
        const int vb = blockIdx.x - 1024;
        const float4 q = ((const float4*)v)[(size_t)vb * 256 + tid];
        double s2 = (double)q.x * q.x + (double)q.y * q.y + (double)q.z * q.z + (double)q.w * q.w;
        s2 = wred_d(s2);
        if (lane == 0) sv[w] = s2;
        __syncthreads();
        if (tid == 0) pv[vb] = sv[0] + sv[1] + sv[2] + sv[3];
    }
}

// ---- kernel 3: finalize stats ----
__global__ __launch_bounds__(256) void k_finalize(const float* __restrict__ gamma,
                                                  const float* __restrict__ beta,
                                                  const float* __restrict__ g,
                                                  const double* __restrict__ pS,
                                                  const double* __restrict__ pS2,
                                                  const double* __restrict__ pv,
                                                  float* __restrict__ ab,
                                                  float* __restrict__ invn) {
    const int tid = threadIdx.x;
    const int lane = tid & 63, w = tid >> 6;
    double s2 = (tid < 192) ? pv[tid] : 0.0;
    s2 = wred_d(s2);
    __shared__ double sv[4];
    if (lane == 0) sv[w] = s2;
    __syncthreads();
    if (tid == 0) invn[0] = (float)((double)g[0] / sqrt(sv[0] + sv[1] + sv[2] + sv[3]));

    const int c = tid;
    double s  = pS[c * 4] + pS[c * 4 + 1] + pS[c * 4 + 2] + pS[c * 4 + 3];
    double ss = pS2[c * 4] + pS2[c * 4 + 1] + pS2[c * 4 + 2] + pS2[c * 4 + 3];
    const double N = (double)NBL;
    double mean = s / N;
    double var = ss / N - mean * mean;
    double rstd = 1.0 / sqrt(var + EPS_);
    double a = (double)gamma[c] * rstd;
    ab[c] = (float)a;
    ab[C_ + c] = (float)((double)beta[c] - mean * a);
}

// ---- kernel 3b: weight prep, f16 single, fragment-major [tap][o16][c8chunk][o&15][c&7];
//      block 0 also zeros the 9 KB halo zero-page ----
__global__ __launch_bounds__(256) void k_wprep(const float* __restrict__ v,
                                               const float* __restrict__ invn,
                                               ushort_t* __restrict__ W,
                                               ushort_t* __restrict__ zp8) {
    const int o = blockIdx.x;
    const int c = threadIdx.x;
    const float sc = invn[0];
    if (blockIdx.x == 0) {
        for (int i = threadIdx.x; i < 4608; i += 256) zp8[i] = 0;
    }
#pragma unroll
    for (int tap = 0; tap < 3; ++tap) {
        float w = v[((size_t)o * C_ + c) * 3 + tap] * sc;
        int idx = ((tap * 16 + (o >> 4)) * 32 + (c >> 3)) * 128 + (o & 15) * 8 + (c & 7);
        W[idx] = f16bits(w);
    }
}

// ---- kernel 4a: tau per row (Michelot projection), no s write ----
__global__ __launch_bounds__(256) void k_tau(const float* __restrict__ x,
                                             const float* __restrict__ ab,
                                             float* __restrict__ tauv) {
    const int row = blockIdx.x;          // b*C + c
    const int c = row & (C_ - 1);
    const int tid = threadIdx.x;
    const int lane = tid & 63, w = tid >> 6;
    __shared__ float svf[4];
    __shared__ int svi[4];
    __shared__ float s_tau;
    __shared__ int s_cnt;

    const float a = ab[c];
    const float bb = ab[C_ + c];
    const float4* px = (const float4*)(x + (size_t)row * L_);

    float z[32];
    float sm = 0.f;
#pragma unroll
    for (int j = 0; j < 8; ++j) {
        float4 q = px[j * 256 + tid];
        float z0 = fmaf(a, q.x, bb), z1 = fmaf(a, q.y, bb);
        float z2 = fmaf(a, q.z, bb), z3 = fmaf(a, q.w, bb);
        z[4 * j] = z0; z[4 * j + 1] = z1; z[4 * j + 2] = z2; z[4 * j + 3] = z3;
        sm += z0 + z1 + z2 + z3;
    }
    sm = wred_f(sm);
    if (lane == 0) svf[w] = sm;
    __syncthreads();
    if (tid == 0) s_tau = (svf[0] + svf[1] + svf[2] + svf[3] - 1.f) * (1.f / (float)L_);
    __syncthreads();
    float tau = s_tau;
    int prev = L_;
    for (int it = 0; it < 100; ++it) {
        float ls = 0.f; int lc = 0;
#pragma unroll
        for (int j = 0; j < 32; ++j) {
            if (z[j] > tau) { ls += z[j]; ++lc; }
        }
        ls = wred_f(ls); lc = wred_i(lc);
        if (lane == 0) { svf[w] = ls; svi[w] = lc; }
        __syncthreads();
        if (tid == 0) {
            int gc = svi[0] + svi[1] + svi[2] + svi[3];
            float gs = svf[0] + svf[1] + svf[2] + svf[3];
            s_cnt = gc;
            s_tau = (gs - 1.f) / (float)gc;
        }
        __syncthreads();
        int gc = s_cnt;
        if (gc == prev) break;
        prev = gc;
        tau = s_tau;
    }
    if (tid == 0) tauv[row] = s_tau;
}

// ---- kernel 4b (fast): fused normalize + sparsemax-apply + f16 + transpose ----
// x[b][c][l] -> Sh[b][l>>4][c>>3][l&15][c&7] f16, grid (L/32, B), 256 thr
__global__ __launch_bounds__(256) void k_applyT(const float* __restrict__ x,
                                                const float* __restrict__ ab,
                                                const float* __restrict__ tauv,
                                                ushort_t* __restrict__ Sh) {
    __shared__ float sT[32 * 256];
    const int lt = blockIdx.x * 32;
    const int b = blockIdx.y;
    const int tid = threadIdx.x;
    {
        const int c = tid;
        const float a = ab[c];
        const float bb = ab[C_ + c];
        const float tv = tauv[b * C_ + c];
        const float* src = x + ((size_t)b * C_ + c) * L_ + lt;
        const int qg = c >> 2, cr = c & 3;
#pragma unroll
        for (int j = 0; j < 8; ++j) {
            float4 v4 = ((const float4*)src)[j];
            int l0 = j * 4;
            float s0 = fmaxf(fmaf(a, v4.x, bb) - tv, 0.f);
            float s1 = fmaxf(fmaf(a, v4.y, bb) - tv, 0.f);
            float s2 = fmaxf(fmaf(a, v4.z, bb) - tv, 0.f);
            float s3 = fmaxf(fmaf(a, v4.w, bb) - tv, 0.f);
            sT[(l0 + 0) * 256 + (((qg ^ ((l0 + 0) & 7)) << 2) | cr)] = s0;
            sT[(l0 + 1) * 256 + (((qg ^ ((l0 + 1) & 7)) << 2) | cr)] = s1;
            sT[(l0 + 2) * 256 + (((qg ^ ((l0 + 2) & 7)) << 2) | cr)] = s2;
            sT[(l0 + 3) * 256 + (((qg ^ ((l0 + 3) & 7)) << 2) | cr)] = s3;
        }
    }
    __syncthreads();
    const int l = tid & 31, c8 = tid >> 5;
    ushort_t hb[32];
#pragma unroll
    for (int i = 0; i < 8; ++i) {
        int qq = c8 * 8 + i;
        const float4 v4 = *(const float4*)&sT[l * 256 + ((qq ^ (l & 7)) << 2)];
        hb[i * 4 + 0] = f16bits(v4.x);
        hb[i * 4 + 1] = f16bits(v4.y);
        hb[i * 4 + 2] = f16bits(v4.z);
        hb[i * 4 + 3] = f16bits(v4.w);
    }
    const size_t tbase = (((size_t)b * 512 + ((lt + l) >> 4)) * 32) * 128 + (l & 15) * 8;
#pragma unroll
    for (int i = 0; i < 4; ++i) {
        size_t idx = tbase + (size_t)(c8 * 4 + i) * 128;
        *(uint4*)(Sh + idx) = ((const uint4*)hb)[i];
    }
}

// ---- legacy fallback: sparsemax writing s fp32 (to d_out) ----
__global__ __launch_bounds__(256) void k_sparsemax(const float* __restrict__ x,
                                                   const float* __restrict__ ab,
                                                   float* __restrict__ sout) {
    const int row = blockIdx.x;
    const int c = row & (C_ - 1);
    const int tid = threadIdx.x;
    const int lane = tid & 63, w = tid >> 6;
    __shared__ float svf[4];
    __shared__ int svi[4];
    __shared__ float s_tau;
    __shared__ int s_cnt;

    const float a = ab[c];
    const float bb = ab[C_ + c];
    const float4* px = (const float4*)(x + (size_t)row * L_);
    float4* ps = (float4*)(sout + (size_t)row * L_);

    float z[32];
    float sm = 0.f;
#pragma unroll
    for (int j = 0; j < 8; ++j) {
        float4 q = px[j * 256 + tid];
        float z0 = fmaf(a, q.x, bb), z1 = fmaf(a, q.y, bb);
        float z2 = fmaf(a, q.z, bb), z3 = fmaf(a, q.w, bb);
        z[4 * j] = z0; z[4 * j + 1] = z1; z[4 * j + 2] = z2; z[4 * j + 3] = z3;
        sm += z0 + z1 + z2 + z3;
    }
    sm = wred_f(sm);
    if (lane == 0) svf[w] = sm;
    __syncthreads();
    if (tid == 0) s_tau = (svf[0] + svf[1] + svf[2] + svf[3] - 1.f) * (1.f / (float)L_);
    __syncthreads();
    float tau = s_tau;
    int prev = L_;
    for (int it = 0; it < 100; ++it) {
        float ls = 0.f; int lc = 0;
#pragma unroll
        for (int j = 0; j < 32; ++j) {
            if (z[j] > tau) { ls += z[j]; ++lc; }
        }
        ls = wred_f(ls); lc = wred_i(lc);
        if (lane == 0) { svf[w] = ls; svi[w] = lc; }
        __syncthreads();
        if (tid == 0) {
            int gc = svi[0] + svi[1] + svi[2] + svi[3];
            float gs = svf[0] + svf[1] + svf[2] + svf[3];
            s_cnt = gc;
            s_tau = (gs - 1.f) / (float)gc;
        }
        __syncthreads();
        int gc = s_cnt;
        if (gc == prev) break;
        prev = gc;
        tau = s_tau;
    }
#pragma unroll
    for (int j = 0; j < 8; ++j) {
        float4 o;
        o.x = fmaxf(z[4 * j]     - tau, 0.f);
        o.y = fmaxf(z[4 * j + 1] - tau, 0.f);
        o.z = fmaxf(z[4 * j + 2] - tau, 0.f);
        o.w = fmaxf(z[4 * j + 3] - tau, 0.f);
        ps[j * 256 + tid] = o;
    }
}

// ---- legacy fallback: transpose fp32 s -> fragment-major f16 ----
__global__ __launch_bounds__(256) void k_transF16(const float* __restrict__ s,
                                                  ushort_t* __restrict__ Sh) {
    __shared__ float sT[32 * 256];
    const int lt = blockIdx.x * 32;
    const int b = blockIdx.y;
    const int tid = threadIdx.x;
    {
        const int c = tid;
        const float* src = s + ((size_t)b * C_ + c) * L_ + lt;
        const int qg = c >> 2, cr = c & 3;
#pragma unroll
        for (int j = 0; j < 8; ++j) {
            float4 v4 = ((const float4*)src)[j];
            int l0 = j * 4;
            sT[(l0 + 0) * 256 + (((qg ^ ((l0 + 0) & 7)) << 2) | cr)] = v4.x;
            sT[(l0 + 1) * 256 + (((qg ^ ((l0 + 1) & 7)) << 2) | cr)] = v4.y;
            sT[(l0 + 2) * 256 + (((qg ^ ((l0 + 2) & 7)) << 2) | cr)] = v4.z;
            sT[(l0 + 3) * 256 + (((qg ^ ((l0 + 3) & 7)) << 2) | cr)] = v4.w;
        }
    }
    __syncthreads();
    const int l = tid & 31, c8 = tid >> 5;
    ushort_t hb[32];
#pragma unroll
    for (int i = 0; i < 8; ++i) {
        int qq = c8 * 8 + i;
        const float4 v4 = *(const float4*)&sT[l * 256 + ((qq ^ (l & 7)) << 2)];
        hb[i * 4 + 0] = f16bits(v4.x);
        hb[i * 4 + 1] = f16bits(v4.y);
        hb[i * 4 + 2] = f16bits(v4.z);
        hb[i * 4 + 3] = f16bits(v4.w);
    }
    const size_t tbase = (((size_t)b * 512 + ((lt + l) >> 4)) * 32) * 128 + (l & 15) * 8;
#pragma unroll
    for (int i = 0; i < 4; ++i) {
        size_t idx = tbase + (size_t)(c8 * 4 + i) * 128;
        *(uint4*)(Sh + idx) = ((const uint4*)hb)[i];
    }
}

// ---- kernel 5: conv, f16 MFMA, LDS-staged B (one barrier), A from global ----
// RESTORED to the round-2 verified configuration: 64 O x 64 L per wave
// (acc[4][4] = 64 regs), unroll 1 on ck loop, launch_bounds(256,2).
// Round-5 post-mortem: unroll 2 + launch_bounds(256,3) forced VGPR 168 -> 84
// with scratch spills (WRITE_SIZE 131 MB -> 166 MB = spill traffic), conv
// 77 -> 110 us. Do NOT tighten the register budget on this kernel.
template<bool EDGE>
__device__ __forceinline__ void conv_core(const ushort_t* __restrict__ Sg,
                                          const ushort_t* __restrict__ W,
                                          const ushort_t* __restrict__ zp8,
                                          float* __restrict__ y,
                                          ushort_t* sB) {
    const int lt = blockIdx.x * 64;
    const int b = blockIdx.y;
    const int tid = threadIdx.x;
    const int wv = tid >> 6, lane = tid & 63;
    const int ml = lane & 15, qd = lane >> 4;

    const ushort_t* SgB = Sg + (size_t)b * 512 * 4096;   // 512 tiles/batch, 4096 elem/tile

    // ---- stage: one contiguous 32 KB global->LDS memcpy ----
    {
        const ushort_t* gsrc = SgB + (size_t)(lt >> 4) * 4096;
        char* lb = (char*)sB;
#pragma unroll
        for (int it = 0; it < 8; ++it) {
            int u = it * 256 + tid;
            __builtin_amdgcn_global_load_lds(
                (const __attribute__((address_space(1))) uint32_t*)(gsrc + u * 8),
                (__attribute__((address_space(3))) uint32_t*)(lb + u * 16),
                16, 0, 0);
        }
    }

    // A-fragment global pointers (per-lane), ck=0 base
    const ushort_t* pA[3][4];
#pragma unroll
    for (int tap = 0; tap < 3; ++tap)
#pragma unroll
        for (int mi = 0; mi < 4; ++mi)
            pA[tap][mi] = W + ((tap * 16 + wv * 4 + mi) * 32 + qd) * 128 + ml * 8;

    // B-fragment LDS byte offsets (ck=0); [0][0] and [2][3] replaced by global
    int bOff[3][4];
#pragma unroll
    for (int tap = 0; tap < 3; ++tap)
#pragma unroll
        for (int ni = 0; ni < 4; ++ni) {
            int rc = ni * 16 + ml + tap - 1;
            int rcc = rc & 63;               // avoid negative shifts; boundary frags unused
            bOff[tap][ni] = ((rcc >> 4) << 13) + (qd << 8) + ((rcc & 15) << 4);
        }

    // boundary fragments via global (per-lane pointers)
    const int ccgL = lt + ml - 1;        // tap0 ni0
    const int ccgR = lt + 49 + ml;       // tap2 ni3
    const ushort_t* gpL;
    const ushort_t* gpR;
    {
        int cl = ccgL & (L_ - 1);
        int cr2 = ccgR & (L_ - 1);
        const ushort_t* pl = SgB + (((size_t)(cl >> 4) * 32 + qd) * 128 + (cl & 15) * 8);
        const ushort_t* pr = SgB + (((size_t)(cr2 >> 4) * 32 + qd) * 128 + (cr2 & 15) * 8);
        if (EDGE) {
            if (ccgL < 0)   pl = zp8;
            if (ccgR >= L_) pr = zp8;
        }
        gpL = pl; gpR = pr;
    }

    f32x4 acc[4][4];
#pragma unroll
    for (int mi = 0; mi < 4; ++mi)
#pragma unroll
        for (int ni = 0; ni < 4; ++ni) acc[mi][ni] = (f32x4)0.f;

    __syncthreads();

    const char* sBc = (const char*)sB;
#pragma unroll 1
    for (int ck = 0; ck < 8; ++ck) {
        const int lofs = ck * 1024;        // bytes: 4 chunks * 256 B
        const int gofs = ck * 512;         // elements
#pragma unroll
        for (int tap = 0; tap < 3; ++tap) {
            f16x8 Bf[4];
#pragma unroll
            for (int ni = 0; ni < 4; ++ni) {
                if (tap == 0 && ni == 0)
                    Bf[ni] = *(const f16x8*)(gpL + gofs);
                else if (tap == 2 && ni == 3)
                    Bf[ni] = *(const f16x8*)(gpR + gofs);
                else
                    Bf[ni] = *(const f16x8*)(sBc + bOff[tap][ni] + lofs);
            }
#pragma unroll
            for (int mi = 0; mi < 4; ++mi) {
                f16x8 Af = *(const f16x8*)(pA[tap][mi] + gofs);
#pragma unroll
                for (int ni = 0; ni < 4; ++ni)
                    acc[mi][ni] = __builtin_amdgcn_mfma_f32_16x16x32_f16(Af, Bf[ni], acc[mi][ni], 0, 0, 0);
            }
        }
    }

    // epilogue: ReLU + store. C/D: col = lane&15 (l), row = qd*4+r (o)
#pragma unroll
    for (int mi = 0; mi < 4; ++mi) {
#pragma unroll
        for (int ni = 0; ni < 4; ++ni) {
            int lg = lt + ni * 16 + ml;
#pragma unroll
            for (int r = 0; r < 4; ++r) {
                int og = wv * 64 + mi * 16 + qd * 4 + r;
                y[((size_t)b * O_ + og) * L_ + lg] = fmaxf(acc[mi][ni][r], 0.f);
            }
        }
    }
}

__global__ __launch_bounds__(256, 2) void k_conv_f16(const ushort_t* __restrict__ Sg,
                                                     const ushort_t* __restrict__ W,
                                                     const ushort_t* __restrict__ zp8,
                                                     float* __restrict__ y) {
    __shared__ ushort_t sB[16384];   // single 32 KB allocation shared by both paths
    if (blockIdx.x == 0 || blockIdx.x == (L_ / 64) - 1)
        conv_core<true>(Sg, W, zp8, y, sB);
    else
        conv_core<false>(Sg, W, zp8, y, sB);
}

extern "C" void kernel_launch(void* const* d_in, const int* in_sizes, int n_in,
                              void* d_out, int out_size, void* d_ws, size_t ws_size,
                              hipStream_t stream) {
    const float* x     = (const float*)d_in[0];
    const float* gamma = (const float*)d_in[1];
    const float* beta  = (const float*)d_in[2];
    const float* v     = (const float*)d_in[3];
    const float* g     = (const float*)d_in[4];
    float* y = (float*)d_out;

    char* ws = (char*)d_ws;
    float*  ab   = (float*)ws;                    // 512 floats
    float*  invn = (float*)(ws + 2048);           // 1 float
    double* pv   = (double*)(ws + 4096);          // 192 doubles
    double* pS   = (double*)(ws + 8192);          // 1024 doubles
    double* pS2  = (double*)(ws + 16384);         // 1024 doubles
    float*  tauv = (float*)(ws + 24576);          // 4096 floats (16 KB)
    ushort_t* W  = (ushort_t*)(ws + 49152);       // 196608 ushorts = 384 KB
    ushort_t* zp8 = (ushort_t*)(ws + 49152 + 393216);  // 4608 ushorts (9 KB zeros)

    const size_t shOff = 1 << 20;                 // Sh at ws + 1 MB
    const size_t need = shOff + (size_t)B_ * L_ * C_ * sizeof(ushort_t);  // 1 MB + 64 MB
    const bool fast = (ws_size >= need);

    k_stats<<<1216, 256, 0, stream>>>(x, v, pS, pS2, pv);
    k_finalize<<<1, 256, 0, stream>>>(gamma, beta, g, pS, pS2, pv, ab, invn);
    k_wprep<<<256, 256, 0, stream>>>(v, invn, W, zp8);

    const ushort_t* Sg;
    if (fast) {
        ushort_t* Sh = (ushort_t*)(ws + shOff);
        k_tau<<<4096, 256, 0, stream>>>(x, ab, tauv);
        dim3 tg(L_ / 32, B_);
        k_applyT<<<tg, 256, 0, stream>>>(x, ab, tauv, Sh);
        Sg = Sh;
    } else {
        // legacy: s fp32 round-trips through d_out; Sh f16 lives in x's buffer
        float* sbuf = (float*)d_out;
        ushort_t* Sh = (ushort_t*)d_in[0];
        k_sparsemax<<<4096, 256, 0, stream>>>(x, ab, sbuf);
        dim3 tg(L_ / 32, B_);
        k_transF16<<<tg, 256, 0, stream>>>(sbuf, Sh);
        Sg = Sh;
    }

    dim3 cgrid(L_ / 64, B_);
    k_conv_f16<<<cgrid, 256, 0, stream>>>(Sg, W, zp8, y);
}

// Round 7
// 363.278 us; speedup vs baseline: 1.1261x; 1.0187x over previous
//
#include <hip/hip_runtime.h>
#include <stdint.h>
#include <math.h>

#define B_ 16
#define C_ 256
#define O_ 256
#define L_ 8192
#define NBL (B_*L_)
#define EPS_ 1e-5

typedef unsigned short ushort_t;
typedef _Float16 f16x8 __attribute__((ext_vector_type(8)));
typedef float f32x4 __attribute__((ext_vector_type(4)));

__device__ inline float wred_f(float v) {
#pragma unroll
    for (int o = 32; o > 0; o >>= 1) v += __shfl_down(v, o, 64);
    return v;
}
__device__ inline int wred_i(int v) {
#pragma unroll
    for (int o = 32; o > 0; o >>= 1) v += __shfl_down(v, o, 64);
    return v;
}
__device__ inline double wred_d(double v) {
#pragma unroll
    for (int o = 32; o > 0; o >>= 1) v += __shfl_down(v, o, 64);
    return v;
}

__device__ inline ushort_t f16bits(float x) {
    union { _Float16 h; ushort_t u; } c; c.h = (_Float16)x; return c.u;
}

// ---- kernel 1 (merged): BN partial sums (blocks 0..1023) + weight-norm
//      partial sumsq (blocks 1024..1215). ----
__global__ __launch_bounds__(256) void k_stats(const float* __restrict__ x,
                                               const float* __restrict__ v,
                                               double* __restrict__ pS,
                                               double* __restrict__ pS2,
                                               double* __restrict__ pv) {
    const int tid = threadIdx.x;
    const int lane = tid & 63, w = tid >> 6;
    __shared__ double sv[4], sv2[4];
    if (blockIdx.x < 1024) {
        const int bid = blockIdx.x;
        const int c = bid >> 2;
        const int part = bid & 3;
        double s = 0.0, s2 = 0.0;
#pragma unroll
        for (int b = 0; b < 4; ++b) {
            const float4* p = (const float4*)(x + ((size_t)(part * 4 + b) * C_ + c) * L_);
#pragma unroll
            for (int j = 0; j < 8; ++j) {
                float4 q = p[j * 256 + tid];
                s  += (double)q.x + (double)q.y + (double)q.z + (double)q.w;
                s2 += (double)q.x * q.x + (double)q.y * q.y + (double)q.z * q.z + (double)q.w * q.w;
            }
        }
        s = wred_d(s); s2 = wred_d(s2);
        if (lane == 0) { sv[w] = s; sv2[w] = s2; }
        __syncthreads();
        if (tid == 0) {
            pS[bid]  = sv[0] + sv[1] + sv[2] + sv[3];
            pS2[bid] = sv2[0] + sv2[1] + sv2[2] + sv2[3];
        }
    } else {
        const int vb = blockIdx.x - 1024;
        const float4 q = ((const float4*)v)[(size_t)vb * 256 + tid];
        double s2 = (double)q.x * q.x + (double)q.y * q.y + (double)q.z * q.z + (double)q.w * q.w;
        s2 = wred_d(s2);
        if (lane == 0) sv[w] = s2;
        __syncthreads();
        if (tid == 0) pv[vb] = sv[0] + sv[1] + sv[2] + sv[3];
    }
}

// ---- kernel 3: finalize stats ----
__global__ __launch_bounds__(256) void k_finalize(const float* __restrict__ gamma,
                                                  const float* __restrict__ beta,
                                                  const float* __restrict__ g,
                                                  const double* __restrict__ pS,
                                                  const double* __restrict__ pS2,
                                                  const double* __restrict__ pv,
                                                  float* __restrict__ ab,
                                                  float* __restrict__ invn) {
    const int tid = threadIdx.x;
    const int lane = tid & 63, w = tid >> 6;
    double s2 = (tid < 192) ? pv[tid] : 0.0;
    s2 = wred_d(s2);
    __shared__ double sv[4];
    if (lane == 0) sv[w] = s2;
    __syncthreads();
    if (tid == 0) invn[0] = (float)((double)g[0] / sqrt(sv[0] + sv[1] + sv[2] + sv[3]));

    const int c = tid;
    double s  = pS[c * 4] + pS[c * 4 + 1] + pS[c * 4 + 2] + pS[c * 4 + 3];
    double ss = pS2[c * 4] + pS2[c * 4 + 1] + pS2[c * 4 + 2] + pS2[c * 4 + 3];
    const double N = (double)NBL;
    double mean = s / N;
    double var = ss / N - mean * mean;
    double rstd = 1.0 / sqrt(var + EPS_);
    double a = (double)gamma[c] * rstd;
    ab[c] = (float)a;
    ab[C_ + c] = (float)((double)beta[c] - mean * a);
}

// ---- kernel 3b: weight prep, f16 single, fragment-major [tap][o16][c8chunk][o&15][c&7];
//      block 0 also zeros the 9 KB halo zero-page ----
__global__ __launch_bounds__(256) void k_wprep(const float* __restrict__ v,
                                               const float* __restrict__ invn,
                                               ushort_t* __restrict__ W,
                                               ushort_t* __restrict__ zp8) {
    const int o = blockIdx.x;
    const int c = threadIdx.x;
    const float sc = invn[0];
    if (blockIdx.x == 0) {
        for (int i = threadIdx.x; i < 4608; i += 256) zp8[i] = 0;
    }
#pragma unroll
    for (int tap = 0; tap < 3; ++tap) {
        float w = v[((size_t)o * C_ + c) * 3 + tap] * sc;
        int idx = ((tap * 16 + (o >> 4)) * 32 + (c >> 3)) * 128 + (o & 15) * 8 + (c & 7);
        W[idx] = f16bits(w);
    }
}

// ---- kernel 4a: tau per row (Michelot projection), no s write ----
__global__ __launch_bounds__(256) void k_tau(const float* __restrict__ x,
                                             const float* __restrict__ ab,
                                             float* __restrict__ tauv) {
    const int row = blockIdx.x;          // b*C + c
    const int c = row & (C_ - 1);
    const int tid = threadIdx.x;
    const int lane = tid & 63, w = tid >> 6;
    __shared__ float svf[4];
    __shared__ int svi[4];
    __shared__ float s_tau;
    __shared__ int s_cnt;

    const float a = ab[c];
    const float bb = ab[C_ + c];
    const float4* px = (const float4*)(x + (size_t)row * L_);

    float z[32];
    float sm = 0.f;
#pragma unroll
    for (int j = 0; j < 8; ++j) {
        float4 q = px[j * 256 + tid];
        float z0 = fmaf(a, q.x, bb), z1 = fmaf(a, q.y, bb);
        float z2 = fmaf(a, q.z, bb), z3 = fmaf(a, q.w, bb);
        z[4 * j] = z0; z[4 * j + 1] = z1; z[4 * j + 2] = z2; z[4 * j + 3] = z3;
        sm += z0 + z1 + z2 + z3;
    }
    sm = wred_f(sm);
    if (lane == 0) svf[w] = sm;
    __syncthreads();
    if (tid == 0) s_tau = (svf[0] + svf[1] + svf[2] + svf[3] - 1.f) * (1.f / (float)L_);
    __syncthreads();
    float tau = s_tau;
    int prev = L_;
    for (int it = 0; it < 100; ++it) {
        float ls = 0.f; int lc = 0;
#pragma unroll
        for (int j = 0; j < 32; ++j) {
            if (z[j] > tau) { ls += z[j]; ++lc; }
        }
        ls = wred_f(ls); lc = wred_i(lc);
        if (lane == 0) { svf[w] = ls; svi[w] = lc; }
        __syncthreads();
        if (tid == 0) {
            int gc = svi[0] + svi[1] + svi[2] + svi[3];
            float gs = svf[0] + svf[1] + svf[2] + svf[3];
            s_cnt = gc;
            s_tau = (gs - 1.f) / (float)gc;
        }
        __syncthreads();
        int gc = s_cnt;
        if (gc == prev) break;
        prev = gc;
        tau = s_tau;
    }
    if (tid == 0) tauv[row] = s_tau;
}

// ---- kernel 4b (fast): fused normalize + sparsemax-apply + f16 + transpose ----
// x[b][c][l] -> Sh[b][l>>4][c>>3][l&15][c&7] f16, grid (L/32, B), 256 thr
__global__ __launch_bounds__(256) void k_applyT(const float* __restrict__ x,
                                                const float* __restrict__ ab,
                                                const float* __restrict__ tauv,
                                                ushort_t* __restrict__ Sh) {
    __shared__ float sT[32 * 256];
    const int lt = blockIdx.x * 32;
    const int b = blockIdx.y;
    const int tid = threadIdx.x;
    {
        const int c = tid;
        const float a = ab[c];
        const float bb = ab[C_ + c];
        const float tv = tauv[b * C_ + c];
        const float* src = x + ((size_t)b * C_ + c) * L_ + lt;
        const int qg = c >> 2, cr = c & 3;
#pragma unroll
        for (int j = 0; j < 8; ++j) {
            float4 v4 = ((const float4*)src)[j];
            int l0 = j * 4;
            float s0 = fmaxf(fmaf(a, v4.x, bb) - tv, 0.f);
            float s1 = fmaxf(fmaf(a, v4.y, bb) - tv, 0.f);
            float s2 = fmaxf(fmaf(a, v4.z, bb) - tv, 0.f);
            float s3 = fmaxf(fmaf(a, v4.w, bb) - tv, 0.f);
            sT[(l0 + 0) * 256 + (((qg ^ ((l0 + 0) & 7)) << 2) | cr)] = s0;
            sT[(l0 + 1) * 256 + (((qg ^ ((l0 + 1) & 7)) << 2) | cr)] = s1;
            sT[(l0 + 2) * 256 + (((qg ^ ((l0 + 2) & 7)) << 2) | cr)] = s2;
            sT[(l0 + 3) * 256 + (((qg ^ ((l0 + 3) & 7)) << 2) | cr)] = s3;
        }
    }
    __syncthreads();
    const int l = tid & 31, c8 = tid >> 5;
    ushort_t hb[32];
#pragma unroll
    for (int i = 0; i < 8; ++i) {
        int qq = c8 * 8 + i;
        const float4 v4 = *(const float4*)&sT[l * 256 + ((qq ^ (l & 7)) << 2)];
        hb[i * 4 + 0] = f16bits(v4.x);
        hb[i * 4 + 1] = f16bits(v4.y);
        hb[i * 4 + 2] = f16bits(v4.z);
        hb[i * 4 + 3] = f16bits(v4.w);
    }
    const size_t tbase = (((size_t)b * 512 + ((lt + l) >> 4)) * 32) * 128 + (l & 15) * 8;
#pragma unroll
    for (int i = 0; i < 4; ++i) {
        size_t idx = tbase + (size_t)(c8 * 4 + i) * 128;
        *(uint4*)(Sh + idx) = ((const uint4*)hb)[i];
    }
}

// ---- legacy fallback: sparsemax writing s fp32 (to d_out) ----
__global__ __launch_bounds__(256) void k_sparsemax(const float* __restrict__ x,
                                                   const float* __restrict__ ab,
                                                   float* __restrict__ sout) {
    const int row = blockIdx.x;
    const int c = row & (C_ - 1);
    const int tid = threadIdx.x;
    const int lane = tid & 63, w = tid >> 6;
    __shared__ float svf[4];
    __shared__ int svi[4];
    __shared__ float s_tau;
    __shared__ int s_cnt;

    const float a = ab[c];
    const float bb = ab[C_ + c];
    const float4* px = (const float4*)(x + (size_t)row * L_);
    float4* ps = (float4*)(sout + (size_t)row * L_);

    float z[32];
    float sm = 0.f;
#pragma unroll
    for (int j = 0; j < 8; ++j) {
        float4 q = px[j * 256 + tid];
        float z0 = fmaf(a, q.x, bb), z1 = fmaf(a, q.y, bb);
        float z2 = fmaf(a, q.z, bb), z3 = fmaf(a, q.w, bb);
        z[4 * j] = z0; z[4 * j + 1] = z1; z[4 * j + 2] = z2; z[4 * j + 3] = z3;
        sm += z0 + z1 + z2 + z3;
    }
    sm = wred_f(sm);
    if (lane == 0) svf[w] = sm;
    __syncthreads();
    if (tid == 0) s_tau = (svf[0] + svf[1] + svf[2] + svf[3] - 1.f) * (1.f / (float)L_);
    __syncthreads();
    float tau = s_tau;
    int prev = L_;
    for (int it = 0; it < 100; ++it) {
        float ls = 0.f; int lc = 0;
#pragma unroll
        for (int j = 0; j < 32; ++j) {
            if (z[j] > tau) { ls += z[j]; ++lc; }
        }
        ls = wred_f(ls); lc = wred_i(lc);
        if (lane == 0) { svf[w] = ls; svi[w] = lc; }
        __syncthreads();
        if (tid == 0) {
            int gc = svi[0] + svi[1] + svi[2] + svi[3];
            float gs = svf[0] + svf[1] + svf[2] + svf[3];
            s_cnt = gc;
            s_tau = (gs - 1.f) / (float)gc;
        }
        __syncthreads();
        int gc = s_cnt;
        if (gc == prev) break;
        prev = gc;
        tau = s_tau;
    }
#pragma unroll
    for (int j = 0; j < 8; ++j) {
        float4 o;
        o.x = fmaxf(z[4 * j]     - tau, 0.f);
        o.y = fmaxf(z[4 * j + 1] - tau, 0.f);
        o.z = fmaxf(z[4 * j + 2] - tau, 0.f);
        o.w = fmaxf(z[4 * j + 3] - tau, 0.f);
        ps[j * 256 + tid] = o;
    }
}

// ---- legacy fallback: transpose fp32 s -> fragment-major f16 ----
__global__ __launch_bounds__(256) void k_transF16(const float* __restrict__ s,
                                                  ushort_t* __restrict__ Sh) {
    __shared__ float sT[32 * 256];
    const int lt = blockIdx.x * 32;
    const int b = blockIdx.y;
    const int tid = threadIdx.x;
    {
        const int c = tid;
        const float* src = s + ((size_t)b * C_ + c) * L_ + lt;
        const int qg = c >> 2, cr = c & 3;
#pragma unroll
        for (int j = 0; j < 8; ++j) {
            float4 v4 = ((const float4*)src)[j];
            int l0 = j * 4;
            sT[(l0 + 0) * 256 + (((qg ^ ((l0 + 0) & 7)) << 2) | cr)] = v4.x;
            sT[(l0 + 1) * 256 + (((qg ^ ((l0 + 1) & 7)) << 2) | cr)] = v4.y;
            sT[(l0 + 2) * 256 + (((qg ^ ((l0 + 2) & 7)) << 2) | cr)] = v4.z;
            sT[(l0 + 3) * 256 + (((qg ^ ((l0 + 3) & 7)) << 2) | cr)] = v4.w;
        }
    }
    __syncthreads();
    const int l = tid & 31, c8 = tid >> 5;
    ushort_t hb[32];
#pragma unroll
    for (int i = 0; i < 8; ++i) {
        int qq = c8 * 8 + i;
        const float4 v4 = *(const float4*)&sT[l * 256 + ((qq ^ (l & 7)) << 2)];
        hb[i * 4 + 0] = f16bits(v4.x);
        hb[i * 4 + 1] = f16bits(v4.y);
        hb[i * 4 + 2] = f16bits(v4.z);
        hb[i * 4 + 3] = f16bits(v4.w);
    }
    const size_t tbase = (((size_t)b * 512 + ((lt + l) >> 4)) * 32) * 128 + (l & 15) * 8;
#pragma unroll
    for (int i = 0; i < 4; ++i) {
        size_t idx = tbase + (size_t)(c8 * 4 + i) * 128;
        *(uint4*)(Sh + idx) = ((const uint4*)hb)[i];
    }
}

// ---- kernel 5: conv, f16 MFMA, LDS-staged B (one barrier), A from global ----
// 64 O x 64 L per wave (acc[4][4] = 64 regs); block 256 thr = 4 waves;
// grid (L/64 = 128, B = 16).
// REGISTER DIET (this round's single change): pA[3][4] pointer array (24 VGPR)
// -> 1 per-lane byte offset + SGPR-folded uniform offsets; bOff[3][4] (12 VGPR)
// -> vb[3] per-lane bases + compile-time ds_read immediates.
// Verified algebra: vb[t] = qd*256 + ((m&15)<<4) + ((m>>4)<<13), m = ml+t-1
// (arith shift handles m=-1 borrow and m=16 carry; matches old bOff on all
// interior/borrow/carry cases; (tap0,ni0) and (tap2,ni3) stay on the global
// gpL/gpR path so the out-of-range LDS combos are never emitted).
// launch_bounds(256,3): with acc=64, unified total ~115-135 <= 170 -> 3 waves/SIMD.
// Spill tripwire: conv WRITE_SIZE must stay ~131 MB (r5 lesson).
template<bool EDGE>
__device__ __forceinline__ void conv_core(const ushort_t* __restrict__ Sg,
                                          const ushort_t* __restrict__ W,
                                          const ushort_t* __restrict__ zp8,
                                          float* __restrict__ y,
                                          ushort_t* sB) {
    const int lt = blockIdx.x * 64;
    const int b = blockIdx.y;
    const int tid = threadIdx.x;
    const int wv = tid >> 6, lane = tid & 63;
    const int ml = lane & 15, qd = lane >> 4;

    const ushort_t* SgB = Sg + (size_t)b * 512 * 4096;   // 512 tiles/batch, 4096 elem/tile

    // ---- stage: one contiguous 32 KB global->LDS memcpy ----
    {
        const ushort_t* gsrc = SgB + (size_t)(lt >> 4) * 4096;
        char* lb = (char*)sB;
#pragma unroll
        for (int it = 0; it < 8; ++it) {
            int u = it * 256 + tid;
            __builtin_amdgcn_global_load_lds(
                (const __attribute__((address_space(1))) uint32_t*)(gsrc + u * 8),
                (__attribute__((address_space(3))) uint32_t*)(lb + u * 16),
                16, 0, 0);
        }
    }

    // A addressing: single per-lane byte offset; (tap,mi,ck) part is a
    // compile-time constant per unrolled instance -> SGPR-folded.
    // byte addr = W + tap*131072 + wv*32768 + mi*8192 + qd*256 + ml*16 + ck*1024
    const char* Wb = (const char*)W;
    const int aoff = wv * 32768 + qd * 256 + ml * 16;

    // B addressing: per-tap per-lane LDS byte base + compile-time immediates.
    int vb[3];
#pragma unroll
    for (int t = 0; t < 3; ++t) {
        int m = ml + t - 1;                                  // -1 .. 16
        vb[t] = qd * 256 + ((m & 15) << 4) + ((m >> 4) << 13);
    }

    // boundary fragments via global (per-lane pointers)
    const int ccgL = lt + ml - 1;        // tap0 ni0
    const int ccgR = lt + 49 + ml;       // tap2 ni3
    const ushort_t* gpL;
    const ushort_t* gpR;
    {
        int cl = ccgL & (L_ - 1);
        int cr2 = ccgR & (L_ - 1);
        const ushort_t* pl = SgB + (((size_t)(cl >> 4) * 32 + qd) * 128 + (cl & 15) * 8);
        const ushort_t* pr = SgB + (((size_t)(cr2 >> 4) * 32 + qd) * 128 + (cr2 & 15) * 8);
        if (EDGE) {
            if (ccgL < 0)   pl = zp8;
            if (ccgR >= L_) pr = zp8;
        }
        gpL = pl; gpR = pr;
    }

    f32x4 acc[4][4];
#pragma unroll
    for (int mi = 0; mi < 4; ++mi)
#pragma unroll
        for (int ni = 0; ni < 4; ++ni) acc[mi][ni] = (f32x4)0.f;

    __syncthreads();

    const char* sBc = (const char*)sB;
#pragma unroll 1
    for (int ck = 0; ck < 8; ++ck) {
#pragma unroll
        for (int tap = 0; tap < 3; ++tap) {
            f16x8 Bf[4];
#pragma unroll
            for (int ni = 0; ni < 4; ++ni) {
                if (tap == 0 && ni == 0)
                    Bf[ni] = *(const f16x8*)(gpL + ck * 512);
                else if (tap == 2 && ni == 3)
                    Bf[ni] = *(const f16x8*)(gpR + ck * 512);
                else
                    Bf[ni] = *(const f16x8*)(sBc + vb[tap] + ni * 8192 + ck * 1024);
            }
#pragma unroll
            for (int mi = 0; mi < 4; ++mi) {
                f16x8 Af = *(const f16x8*)(Wb + aoff + tap * 131072 + mi * 8192 + ck * 1024);
#pragma unroll
                for (int ni = 0; ni < 4; ++ni)
                    acc[mi][ni] = __builtin_amdgcn_mfma_f32_16x16x32_f16(Af, Bf[ni], acc[mi][ni], 0, 0, 0);
            }
        }
    }

    // epilogue: ReLU + store. C/D: col = lane&15 (l), row = qd*4+r (o)
#pragma unroll
    for (int mi = 0; mi < 4; ++mi) {
#pragma unroll
        for (int ni = 0; ni < 4; ++ni) {
            int lg = lt + ni * 16 + ml;
#pragma unroll
            for (int r = 0; r < 4; ++r) {
                int og = wv * 64 + mi * 16 + qd * 4 + r;
                y[((size_t)b * O_ + og) * L_ + lg] = fmaxf(acc[mi][ni][r], 0.f);
            }
        }
    }
}

__global__ __launch_bounds__(256, 3) void k_conv_f16(const ushort_t* __restrict__ Sg,
                                                     const ushort_t* __restrict__ W,
                                                     const ushort_t* __restrict__ zp8,
                                                     float* __restrict__ y) {
    __shared__ ushort_t sB[16384];   // single 32 KB allocation shared by both paths
    if (blockIdx.x == 0 || blockIdx.x == (L_ / 64) - 1)
        conv_core<true>(Sg, W, zp8, y, sB);
    else
        conv_core<false>(Sg, W, zp8, y, sB);
}

extern "C" void kernel_launch(void* const* d_in, const int* in_sizes, int n_in,
                              void* d_out, int out_size, void* d_ws, size_t ws_size,
                              hipStream_t stream) {
    const float* x     = (const float*)d_in[0];
    const float* gamma = (const float*)d_in[1];
    const float* beta  = (const float*)d_in[2];
    const float* v     = (const float*)d_in[3];
    const float* g     = (const float*)d_in[4];
    float* y = (float*)d_out;

    char* ws = (char*)d_ws;
    float*  ab   = (float*)ws;                    // 512 floats
    float*  invn = (float*)(ws + 2048);           // 1 float
    double* pv   = (double*)(ws + 4096);          // 192 doubles
    double* pS   = (double*)(ws + 8192);          // 1024 doubles
    double* pS2  = (double*)(ws + 16384);         // 1024 doubles
    float*  tauv = (float*)(ws + 24576);          // 4096 floats (16 KB)
    ushort_t* W  = (ushort_t*)(ws + 49152);       // 196608 ushorts = 384 KB
    ushort_t* zp8 = (ushort_t*)(ws + 49152 + 393216);  // 4608 ushorts (9 KB zeros)

    const size_t shOff = 1 << 20;                 // Sh at ws + 1 MB
    const size_t need = shOff + (size_t)B_ * L_ * C_ * sizeof(ushort_t);  // 1 MB + 64 MB
    const bool fast = (ws_size >= need);

    k_stats<<<1216, 256, 0, stream>>>(x, v, pS, pS2, pv);
    k_finalize<<<1, 256, 0, stream>>>(gamma, beta, g, pS, pS2, pv, ab, invn);
    k_wprep<<<256, 256, 0, stream>>>(v, invn, W, zp8);

    const ushort_t* Sg;
    if (fast) {
        ushort_t* Sh = (ushort_t*)(ws + shOff);
        k_tau<<<4096, 256, 0, stream>>>(x, ab, tauv);
        dim3 tg(L_ / 32, B_);
        k_applyT<<<tg, 256, 0, stream>>>(x, ab, tauv, Sh);
        Sg = Sh;
    } else {
        // legacy: s fp32 round-trips through d_out; Sh f16 lives in x's buffer
        float* sbuf = (float*)d_out;
        ushort_t* Sh = (ushort_t*)d_in[0];
        k_sparsemax<<<4096, 256, 0, stream>>>(x, ab, sbuf);
        dim3 tg(L_ / 32, B_);
        k_transF16<<<tg, 256, 0, stream>>>(sbuf, Sh);
        Sg = Sh;
    }

    dim3 cgrid(L_ / 64, B_);
    k_conv_f16<<<cgrid, 256, 0, stream>>>(Sg, W, zp8, y);
}